// Round 1
// baseline (54.010 us; speedup 1.0000x reference)
//
#include <hip/hip_runtime.h>

#define NCLASSES 6

__device__ __forceinline__ float wave_reduce_sum(float v) {
#pragma unroll
    for (int off = 32; off > 0; off >>= 1)
        v += __shfl_down(v, off, 64);
    return v;
}

// Kernel 1: per-block partial {sum, count} per class.
// partials layout: [block][12] = {sum0..sum5, cnt0..cnt5}
__global__ void __launch_bounds__(256)
mae_partial_kernel(const float* __restrict__ inputs,
                   const float* __restrict__ targets,
                   float* __restrict__ partials,
                   int n) {
    float sums[NCLASSES] = {0.f, 0.f, 0.f, 0.f, 0.f, 0.f};
    float cnts[NCLASSES] = {0.f, 0.f, 0.f, 0.f, 0.f, 0.f};

    const int tid = blockIdx.x * blockDim.x + threadIdx.x;
    const int nthreads = gridDim.x * blockDim.x;
    const int n4 = n >> 2;

    const float4* __restrict__ in4 = reinterpret_cast<const float4*>(inputs);
    const float4* __restrict__ tg4 = reinterpret_cast<const float4*>(targets);

    for (int i = tid; i < n4; i += nthreads) {
        float4 x = in4[i];
        float4 t = tg4[i];

        float xs[4] = {x.x, x.y, x.z, x.w};
        float ts[4] = {t.x, t.y, t.z, t.w};
#pragma unroll
        for (int j = 0; j < 4; ++j) {
            float ad = fabsf(xs[j] - ts[j]);
#pragma unroll
            for (int k = 0; k < NCLASSES; ++k) {
                bool m = (ts[j] == (float)k);
                sums[k] += m ? ad : 0.f;
                cnts[k] += m ? 1.f : 0.f;
            }
        }
    }

    // scalar tail (n not divisible by 4)
    const int tail_start = n4 << 2;
    for (int i = tail_start + tid; i < n; i += nthreads) {
        float t = targets[i];
        float ad = fabsf(inputs[i] - t);
#pragma unroll
        for (int k = 0; k < NCLASSES; ++k) {
            bool m = (t == (float)k);
            sums[k] += m ? ad : 0.f;
            cnts[k] += m ? 1.f : 0.f;
        }
    }

    // Block reduce: wave shuffle -> LDS across 4 waves.
    __shared__ float lds[4][12];
    const int lane = threadIdx.x & 63;
    const int wave = threadIdx.x >> 6;

#pragma unroll
    for (int k = 0; k < NCLASSES; ++k) {
        float s = wave_reduce_sum(sums[k]);
        float c = wave_reduce_sum(cnts[k]);
        if (lane == 0) {
            lds[wave][k] = s;
            lds[wave][k + NCLASSES] = c;
        }
    }
    __syncthreads();

    if (threadIdx.x < 12) {
        float v = lds[0][threadIdx.x] + lds[1][threadIdx.x] +
                  lds[2][threadIdx.x] + lds[3][threadIdx.x];
        partials[blockIdx.x * 12 + threadIdx.x] = v;
    }
}

// Kernel 2: deterministic reduce of [nblocks][12] partials -> scalar.
__global__ void __launch_bounds__(256)
mae_finalize_kernel(const float* __restrict__ partials, int nblocks,
                    float* __restrict__ out) {
    float acc[12];
#pragma unroll
    for (int k = 0; k < 12; ++k) acc[k] = 0.f;

    for (int b = threadIdx.x; b < nblocks; b += blockDim.x) {
#pragma unroll
        for (int k = 0; k < 12; ++k) acc[k] += partials[b * 12 + k];
    }

    __shared__ float lds[4][12];
    const int lane = threadIdx.x & 63;
    const int wave = threadIdx.x >> 6;

#pragma unroll
    for (int k = 0; k < 12; ++k) {
        float v = wave_reduce_sum(acc[k]);
        if (lane == 0) lds[wave][k] = v;
    }
    __syncthreads();

    if (threadIdx.x == 0) {
        float total = 0.f;
#pragma unroll
        for (int c = 0; c < NCLASSES; ++c) {
            float s = lds[0][c] + lds[1][c] + lds[2][c] + lds[3][c];
            float n = lds[0][c + NCLASSES] + lds[1][c + NCLASSES] +
                      lds[2][c + NCLASSES] + lds[3][c + NCLASSES];
            total += (n > 0.f) ? (s / n) : 0.f;
        }
        out[0] = total / (float)NCLASSES;
    }
}

extern "C" void kernel_launch(void* const* d_in, const int* in_sizes, int n_in,
                              void* d_out, int out_size, void* d_ws, size_t ws_size,
                              hipStream_t stream) {
    const float* inputs  = (const float*)d_in[0];
    const float* targets = (const float*)d_in[1];
    float* out = (float*)d_out;
    float* partials = (float*)d_ws;

    const int n = in_sizes[0];
    const int NB = 2048;   // memory-bound grid cap per G11; 96 KB of partials in d_ws

    mae_partial_kernel<<<NB, 256, 0, stream>>>(inputs, targets, partials, n);
    mae_finalize_kernel<<<1, 256, 0, stream>>>(partials, NB, out);
}